// Round 8
// baseline (718.171 us; speedup 1.0000x reference)
//
#include <hip/hip_runtime.h>

// RNN: h_{t+1} = tanh(W h_t + w_bias + V x_t + v_bias)
// x: [S,B,I] f32; out = h_seq [S,B,H] f32 ++ h_final [B,H] f32.
// S=2048 B=2048 I=16 H=64.
//
// R8: all-bf16 MFMA experiment. R7 (f16 x32 + legacy 16x16x16f16) failed at
// absmax~1.0 (uncorrelated-output regime). Desk-check of swizzle/staging/
// epilogue is clean; shared-k-permutation invariance rules out within-lane
// k-order. Remaining suspects = per-dtype lane maps: ALL guide-verified
// layout facts are bf16-x32 (m89/m91/m92/m97); f16-x32 and legacy-x16 are
// unverified. This round uses ONLY mfma_f32_16x16x32_bf16 (short8 frags per
// guide example), with V-x zero-padded to K=32 (layout-agnostic by
// construction). Outcomes: ~1.0 -> my structure is broken; ~1e-2 -> layout
// validated (numerics margin tracked separately).
//
// Block = 16 batch rows, 4 waves; wave w computes outs [16w,16w+16).
// h in LDS bf16 [batch][64], 128B rows, double-buffered, XOR-swizzled
// (byte ^= (batch&7)<<4). One barrier per step. x staged 32 steps as bf16.

typedef short  short8v  __attribute__((ext_vector_type(8)));
typedef float  f32x4    __attribute__((ext_vector_type(4)));
typedef unsigned int   u32x4    __attribute__((ext_vector_type(4)));
typedef unsigned short ushort4v __attribute__((ext_vector_type(4)));

constexpr int S = 2048, B = 2048, I = 16, H = 64;
constexpr int RB  = 16;   // batch rows per block
constexpr int CHX = 32;   // steps of x staged per chunk
constexpr int XROW = 20;  // ushort per x row (16 + 4 pad)

// f32 -> bf16 (RNE) bit pattern
static __device__ __forceinline__ unsigned short f2bf(float f) {
    unsigned u = __builtin_bit_cast(unsigned, f);
    return (unsigned short)((u + 0x7FFFu + ((u >> 16) & 1u)) >> 16);
}

__global__ __launch_bounds__(256)
__attribute__((amdgpu_waves_per_eu(1, 2)))
void rnn_mfma(const float* __restrict__ x,
              const float* __restrict__ Wm,
              const float* __restrict__ wb,
              const float* __restrict__ Vm,
              const float* __restrict__ vb,
              float* __restrict__ out)
{
    const int tid = threadIdx.x;
    const int l   = tid & 63;          // lane
    const int w   = tid >> 6;          // wave 0..3
    const int row = l & 15;            // A-row (batch) / B-col (out)
    const int g   = l >> 4;            // k-group
    const int b0  = blockIdx.x * RB;   // global batch base

    __shared__ __align__(16) unsigned short hbuf[2][RB * H];      // 2 x 2KB
    __shared__ __align__(16) unsigned short xbuf[CHX][RB][XROW];  // 20KB

    // ---- B-fragments (weights) in registers, bf16 ----
    // lane: n = 16w+row (out), k = 32s + 8g + j (slice s=0,1)
    const int n = 16 * w + row;
    short8v Wf0, Wf1, Vf8;
    {
        const float* s0 = Wm + n * H + 8 * g;
#pragma unroll
        for (int j = 0; j < 8; ++j) {
            Wf0[j] = (short)f2bf(s0[j]);
            Wf1[j] = (short)f2bf(s0[32 + j]);
        }
        const float* sv = Vm + n * I + 4 * g;
#pragma unroll
        for (int j = 0; j < 4; ++j) {
            Vf8[j]     = (short)f2bf(sv[j]);
            Vf8[j + 4] = 0;                      // zero-pad upper K
        }
    }
    const float bias = wb[n] + vb[n];

    // ---- h0 = 0 ----
    for (int q = tid; q < RB * H; q += 256) hbuf[0][q] = 0;
    __syncthreads();

    // per-lane constant byte offsets into h rows (128 B each), XOR-swizzled
    const int swzr  = (row & 7) << 4;
    const int hoff0 = row * 128 + ((16 * g)      ^ swzr);   // k = 8g..8g+7
    const int hoff1 = row * 128 + ((16 * g + 64) ^ swzr);   // k = 32+8g..

    for (int c = 0; c < S / CHX; ++c) {
        const int t0 = c * CHX;
        // ---- stage x[t0..t0+CHX) for rows b0..b0+15 as bf16 ----
#pragma unroll
        for (int m = 0; m < (CHX * RB * I) / (4 * 256); ++m) {  // 8 float4/thread
            int q  = tid + 256 * m;          // float4 index in chunk
            int tc = q >> 6;                 // 64 float4 per step
            int rr = (q >> 2) & 15;
            int i4 = q & 3;
            float4 t4 = *(const float4*)(x + ((size_t)(t0 + tc) * B + b0 + rr) * I + 4 * i4);
            ushort4v p;
            p[0] = f2bf(t4.x); p[1] = f2bf(t4.y);
            p[2] = f2bf(t4.z); p[3] = f2bf(t4.w);
            *(ushort4v*)(&xbuf[tc][rr][4 * i4]) = p;   // 8B LDS write
        }
        __syncthreads();

        for (int tc = 0; tc < CHX; ++tc) {
            const int t = t0 + tc;
            const char* hb = (const char*)hbuf[t & 1];
            char*       hn = (char*)hbuf[(t + 1) & 1];

            short8v Ah0 = *(const short8v*)(hb + hoff0);
            short8v Ah1 = *(const short8v*)(hb + hoff1);

            // x fragment: 4 real bf16 (k=4g..4g+3 of 16) + zero-padded upper
            uint2 xq = *(const uint2*)(&xbuf[tc][row][4 * g]);
            u32x4 xt; xt[0] = xq.x; xt[1] = xq.y; xt[2] = 0u; xt[3] = 0u;
            short8v Ax8 = __builtin_bit_cast(short8v, xt);

            f32x4 acc = {bias, bias, bias, bias};
            acc = __builtin_amdgcn_mfma_f32_16x16x32_bf16(Ah0, Wf0, acc, 0, 0, 0);
            acc = __builtin_amdgcn_mfma_f32_16x16x32_bf16(Ah1, Wf1, acc, 0, 0, 0);
            acc = __builtin_amdgcn_mfma_f32_16x16x32_bf16(Ax8, Vf8, acc, 0, 0, 0);

            float* ob = out + ((size_t)t * B + b0) * H;
#pragma unroll
            for (int r = 0; r < 4; ++r) {
                // D: batch = 4g+r (row, reg-varying), out = n (col, lane&15)
                float p  = acc[r];
                float e  = __builtin_amdgcn_exp2f(p * 2.8853900817779268f);
                float hv = fmaf(-2.0f, __builtin_amdgcn_rcpf(e + 1.0f), 1.0f);
                int batch = 4 * g + r;
                ob[(size_t)batch * H + n] = hv;                        // h_seq f32
                *(unsigned short*)(hn + batch * 128 + ((2 * n) ^ ((batch & 7) << 4)))
                    = f2bf(hv);                                        // feedback
                if (t == S - 1)                                        // h_final
                    out[(size_t)S * B * H + (size_t)(b0 + batch) * H + n] = hv;
            }
            __syncthreads();
        }
    }
}

extern "C" void kernel_launch(void* const* d_in, const int* in_sizes, int n_in,
                              void* d_out, int out_size, void* d_ws, size_t ws_size,
                              hipStream_t stream) {
    const float* x  = (const float*)d_in[0];
    const float* Wm = (const float*)d_in[1];
    const float* wb = (const float*)d_in[2];
    const float* Vm = (const float*)d_in[3];
    const float* vb = (const float*)d_in[4];
    float* out = (float*)d_out;

    rnn_mfma<<<B / RB, 256, 0, stream>>>(x, Wm, wb, Vm, vb, out);
}

// Round 9
// 697.749 us; speedup vs baseline: 1.0293x; 1.0293x over previous
//
#include <hip/hip_runtime.h>

// RNN: h_{t+1} = tanh(W h_t + w_bias + V x_t + v_bias)
// x: [S,B,I] f32; out = h_seq [S,B,H] f32 ++ h_final [B,H] f32.
// S=2048 B=2048 I=16 H=64.
//
// R9: kill the per-step vmcnt(0) drain. R8 measured 867 cyc/step critical
// path (MfmaUtil 2.8%, VALUBusy 15%) — __syncthreads() emits
// s_waitcnt vmcnt(0) lgkmcnt(0) before s_barrier, so the 4 scattered h_seq
// HBM stores (~400-900 cyc) are drained on the recurrence critical path
// every step. Fix: raw s_barrier + inline-asm lgkmcnt(0) only (cross-wave
// LDS visibility is all correctness needs; h_seq stores are fire-and-forget).
// Also: MFMA accumulator split into 2 independent chains (3 -> 2 dependent
// MFMAs), ds_write feedback issued before global stores.
//
// Structure (validated R8): block = 16 batch rows x 4 waves; wave w owns
// outs [16w,16w+16). mfma_f32_16x16x32_bf16 only; V-x zero-padded to K=32.
// h in LDS bf16 [batch][64], double-buffered, XOR-swizzled
// (byte ^= (batch&7)<<4). x staged 32 steps/chunk as bf16.

typedef short  short8v  __attribute__((ext_vector_type(8)));
typedef float  f32x4    __attribute__((ext_vector_type(4)));
typedef unsigned int   u32x4    __attribute__((ext_vector_type(4)));
typedef unsigned short ushort4v __attribute__((ext_vector_type(4)));

constexpr int S = 2048, B = 2048, I = 16, H = 64;
constexpr int RB  = 16;   // batch rows per block
constexpr int CHX = 32;   // steps of x staged per chunk
constexpr int XROW = 20;  // ushort per x row (16 + 4 pad)

// f32 -> bf16 (RNE) bit pattern
static __device__ __forceinline__ unsigned short f2bf(float f) {
    unsigned u = __builtin_bit_cast(unsigned, f);
    return (unsigned short)((u + 0x7FFFu + ((u >> 16) & 1u)) >> 16);
}

// Barrier with LDS-only drain: global stores stay in flight (no vmcnt).
#define LDS_BARRIER()                                         \
    do {                                                      \
        asm volatile("s_waitcnt lgkmcnt(0)" ::: "memory");    \
        __builtin_amdgcn_s_barrier();                         \
        asm volatile("" ::: "memory");                        \
    } while (0)

__global__ __launch_bounds__(256)
__attribute__((amdgpu_waves_per_eu(1, 2)))
void rnn_mfma(const float* __restrict__ x,
              const float* __restrict__ Wm,
              const float* __restrict__ wb,
              const float* __restrict__ Vm,
              const float* __restrict__ vb,
              float* __restrict__ out)
{
    const int tid = threadIdx.x;
    const int l   = tid & 63;          // lane
    const int w   = tid >> 6;          // wave 0..3
    const int row = l & 15;            // A-row (batch) / B-col (out)
    const int g   = l >> 4;            // k-group
    const int b0  = blockIdx.x * RB;   // global batch base

    __shared__ __align__(16) unsigned short hbuf[2][RB * H];      // 2 x 2KB
    __shared__ __align__(16) unsigned short xbuf[CHX][RB][XROW];  // 20KB

    // ---- B-fragments (weights) in registers, bf16 ----
    // lane: n = 16w+row (out), k = 32s + 8g + j (slice s=0,1)
    const int n = 16 * w + row;
    short8v Wf0, Wf1, Vf8;
    {
        const float* s0 = Wm + n * H + 8 * g;
#pragma unroll
        for (int j = 0; j < 8; ++j) {
            Wf0[j] = (short)f2bf(s0[j]);
            Wf1[j] = (short)f2bf(s0[32 + j]);
        }
        const float* sv = Vm + n * I + 4 * g;
#pragma unroll
        for (int j = 0; j < 4; ++j) {
            Vf8[j]     = (short)f2bf(sv[j]);
            Vf8[j + 4] = 0;                      // zero-pad upper K
        }
    }
    const float bias = wb[n] + vb[n];

    // ---- h0 = 0 ----
    for (int q = tid; q < RB * H; q += 256) hbuf[0][q] = 0;
    __syncthreads();

    // per-lane constant byte offsets into h rows (128 B each), XOR-swizzled
    const int swzr  = (row & 7) << 4;
    const int hoff0 = row * 128 + ((16 * g)      ^ swzr);   // k = 8g..8g+7
    const int hoff1 = row * 128 + ((16 * g + 64) ^ swzr);   // k = 32+8g..

    for (int c = 0; c < S / CHX; ++c) {
        const int t0 = c * CHX;
        // ---- stage x[t0..t0+CHX) for rows b0..b0+15 as bf16 ----
#pragma unroll
        for (int m = 0; m < (CHX * RB * I) / (4 * 256); ++m) {  // 8 float4/thread
            int q  = tid + 256 * m;          // float4 index in chunk
            int tc = q >> 6;                 // 64 float4 per step
            int rr = (q >> 2) & 15;
            int i4 = q & 3;
            float4 t4 = *(const float4*)(x + ((size_t)(t0 + tc) * B + b0 + rr) * I + 4 * i4);
            ushort4v p;
            p[0] = f2bf(t4.x); p[1] = f2bf(t4.y);
            p[2] = f2bf(t4.z); p[3] = f2bf(t4.w);
            *(ushort4v*)(&xbuf[tc][rr][4 * i4]) = p;   // 8B LDS write
        }
        LDS_BARRIER();

        for (int tc = 0; tc < CHX; ++tc) {
            const int t = t0 + tc;
            const char* hb = (const char*)hbuf[t & 1];
            char*       hn = (char*)hbuf[(t + 1) & 1];

            short8v Ah0 = *(const short8v*)(hb + hoff0);
            short8v Ah1 = *(const short8v*)(hb + hoff1);

            // x fragment: 4 real bf16 (k=4g..4g+3 of 16) + zero-padded upper
            uint2 xq = *(const uint2*)(&xbuf[tc][row][4 * g]);
            u32x4 xt; xt[0] = xq.x; xt[1] = xq.y; xt[2] = 0u; xt[3] = 0u;
            short8v Ax8 = __builtin_bit_cast(short8v, xt);

            // two independent accumulator chains (2-deep MFMA dependency)
            f32x4 acc0 = {bias, bias, bias, bias};
            f32x4 acc1 = {0.f, 0.f, 0.f, 0.f};
            acc0 = __builtin_amdgcn_mfma_f32_16x16x32_bf16(Ah0, Wf0, acc0, 0, 0, 0);
            acc1 = __builtin_amdgcn_mfma_f32_16x16x32_bf16(Ah1, Wf1, acc1, 0, 0, 0);
            acc1 = __builtin_amdgcn_mfma_f32_16x16x32_bf16(Ax8, Vf8, acc1, 0, 0, 0);

            float* ob = out + ((size_t)t * B + b0) * H;
            float hv[4];
#pragma unroll
            for (int r = 0; r < 4; ++r) {
                // D: batch = 4g+r (row, reg-varying), out = n (col, lane&15)
                float p  = acc0[r] + acc1[r];
                float e  = __builtin_amdgcn_exp2f(p * 2.8853900817779268f);
                hv[r] = fmaf(-2.0f, __builtin_amdgcn_rcpf(e + 1.0f), 1.0f);
                int batch = 4 * g + r;
                // feedback first: this is what the barrier waits on
                *(unsigned short*)(hn + batch * 128 + ((2 * n) ^ ((batch & 7) << 4)))
                    = f2bf(hv[r]);
            }
#pragma unroll
            for (int r = 0; r < 4; ++r) {    // fire-and-forget HBM stores
                int batch = 4 * g + r;
                ob[(size_t)batch * H + n] = hv[r];
                if (t == S - 1)
                    out[(size_t)S * B * H + (size_t)(b0 + batch) * H + n] = hv[r];
            }
            LDS_BARRIER();
        }
    }
}

extern "C" void kernel_launch(void* const* d_in, const int* in_sizes, int n_in,
                              void* d_out, int out_size, void* d_ws, size_t ws_size,
                              hipStream_t stream) {
    const float* x  = (const float*)d_in[0];
    const float* Wm = (const float*)d_in[1];
    const float* wb = (const float*)d_in[2];
    const float* Vm = (const float*)d_in[3];
    const float* vb = (const float*)d_in[4];
    float* out = (float*)d_out;

    rnn_mfma<<<B / RB, 256, 0, stream>>>(x, Wm, wb, Vm, vb, out);
}